// Round 11
// baseline (205.086 us; speedup 1.0000x reference)
//
#include <hip/hip_runtime.h>
#include <hip/hip_bf16.h>

#define S_LEN 4096
#define NEG_INF_F (-1e30f)

typedef __attribute__((ext_vector_type(4))) float f32x4;
typedef __attribute__((ext_vector_type(8))) short s16x8;
typedef unsigned short u16;

static __device__ __forceinline__ u16 f2bf(float f) {
    unsigned u = __builtin_bit_cast(unsigned, f);
    unsigned r = u + 0x7FFFu + ((u >> 16) & 1u);
    return (u16)(r >> 16);
}
static __device__ __forceinline__ float bf2f(u16 h) {
    unsigned u = ((unsigned)h) << 16;
    return __builtin_bit_cast(float, u);
}
static __device__ __forceinline__ void split4(const float4 v, ushort4& hi, ushort4& lo) {
    hi.x = f2bf(v.x); lo.x = f2bf(v.x - bf2f(hi.x));
    hi.y = f2bf(v.y); lo.y = f2bf(v.y - bf2f(hi.y));
    hi.z = f2bf(v.z); lo.z = f2bf(v.z - bf2f(hi.z));
    hi.w = f2bf(v.w); lo.w = f2bf(v.w - bf2f(hi.w));
}
static __device__ __forceinline__ void gl_lds16(const void* g, void* l) {
    __builtin_amdgcn_global_load_lds(
        (const __attribute__((address_space(1))) void*)g,
        (__attribute__((address_space(3))) void*)l, 16, 0, 0);
}
// swizzled u16 offset within a [rows][64 u16] LDS tile
static __device__ __forceinline__ int swz64(int row, int col_u16) {
    return row * 64 + (col_u16 ^ ((row & 7) << 3));
}
// swizzled u16 offset within a [rows][320 u16] LDS tile
static __device__ __forceinline__ int swz320(int row, int col_u16) {
    return row * 320 + (col_u16 ^ ((row & 7) << 3));
}
// XCD-chunked bijective swizzle for nwg=512
static __device__ __forceinline__ int xcd_swz512(int bid) {
    return (bid & 7) * 64 + (bid >> 3);
}

// ---------------- K0: split x -> xh, xl AND xT (fused transpose) ----------------
__global__ __launch_bounds__(256) void split_xt_kernel(
    const float* __restrict__ x, u16* __restrict__ xh, u16* __restrict__ xl,
    u16* __restrict__ xT) {
    const int bid = blockIdx.x;
    const int dt = bid & 7, st = (bid >> 3) & 63, b = bid >> 9;
    const int s0 = st * 64, d0 = dt * 64;
    __shared__ u16 T[64][72];
    const int tid = threadIdx.x;
    #pragma unroll
    for (int i = 0; i < 4; ++i) {
        int idx = i * 256 + tid;
        int r = idx >> 4, c4 = (idx & 15) * 4;
        float4 v = *(const float4*)(x + (size_t)(b * S_LEN + s0 + r) * 512 + d0 + c4);
        ushort4 hi, lo; split4(v, hi, lo);
        *(ushort4*)(xh + (size_t)(b * S_LEN + s0 + r) * 512 + d0 + c4) = hi;
        *(ushort4*)(xl + (size_t)(b * S_LEN + s0 + r) * 512 + d0 + c4) = lo;
        *(ushort4*)&T[r][c4] = hi;
    }
    __syncthreads();
    #pragma unroll
    for (int i = 0; i < 2; ++i) {
        int idx = i * 256 + tid;
        int dr = idx >> 3, sc = idx & 7;
        s16x8 v;
        #pragma unroll
        for (int t = 0; t < 8; ++t) v[t] = (short)T[sc * 8 + t][dr];
        *(s16x8*)&xT[(size_t)(b * 512 + d0 + dr) * S_LEN + s0 + sc * 8] = v;
    }
}

// ---------------- K1: Mt = Wk^T @ Wq ----------------
__global__ __launch_bounds__(256) void mt_kernel(
    const float* __restrict__ Wk, const float* __restrict__ Wq,
    u16* __restrict__ Mth, u16* __restrict__ Mtl) {
    const int bm = blockIdx.x & 7, bn = blockIdx.x >> 3;
    const int m0 = bm * 64, n0 = bn * 64;
    __shared__ __align__(16) u16 Ath[64 * 72], Atl[64 * 72];
    __shared__ __align__(16) u16 Bth[64 * 72], Btl[64 * 72];
    const int tid = threadIdx.x, lane = tid & 63, w = tid >> 6;
    const int frow = lane & 15, fk = (lane >> 4) * 8;
    f32x4 acc[4] = {};

    for (int h0 = 0; h0 < 512; h0 += 64) {
        #pragma unroll
        for (int i = 0; i < 4; ++i) {
            int idx = i * 256 + tid;
            int h = idx >> 4, c4 = (idx & 15) * 4;
            float4 a = *(const float4*)(Wk + (size_t)(h0 + h) * 512 + m0 + c4);
            ushort4 ahi, alo; split4(a, ahi, alo);
            Ath[(c4 + 0) * 72 + h] = ahi.x; Atl[(c4 + 0) * 72 + h] = alo.x;
            Ath[(c4 + 1) * 72 + h] = ahi.y; Atl[(c4 + 1) * 72 + h] = alo.y;
            Ath[(c4 + 2) * 72 + h] = ahi.z; Atl[(c4 + 2) * 72 + h] = alo.z;
            Ath[(c4 + 3) * 72 + h] = ahi.w; Atl[(c4 + 3) * 72 + h] = alo.w;
            float4 b = *(const float4*)(Wq + (size_t)(h0 + h) * 512 + n0 + c4);
            ushort4 bhi, blo; split4(b, bhi, blo);
            Bth[(c4 + 0) * 72 + h] = bhi.x; Btl[(c4 + 0) * 72 + h] = blo.x;
            Bth[(c4 + 1) * 72 + h] = bhi.y; Btl[(c4 + 1) * 72 + h] = blo.y;
            Bth[(c4 + 2) * 72 + h] = bhi.z; Btl[(c4 + 2) * 72 + h] = blo.z;
            Bth[(c4 + 3) * 72 + h] = bhi.w; Btl[(c4 + 3) * 72 + h] = blo.w;
        }
        __syncthreads();
        #pragma unroll
        for (int kk = 0; kk < 2; ++kk) {
            s16x8 aH = *(const s16x8*)&Ath[(w * 16 + frow) * 72 + kk * 32 + fk];
            s16x8 aL = *(const s16x8*)&Atl[(w * 16 + frow) * 72 + kk * 32 + fk];
            #pragma unroll
            for (int ni = 0; ni < 4; ++ni) {
                s16x8 bH = *(const s16x8*)&Bth[(ni * 16 + frow) * 72 + kk * 32 + fk];
                s16x8 bL = *(const s16x8*)&Btl[(ni * 16 + frow) * 72 + kk * 32 + fk];
                acc[ni] = __builtin_amdgcn_mfma_f32_16x16x32_bf16(aH, bH, acc[ni], 0, 0, 0);
                acc[ni] = __builtin_amdgcn_mfma_f32_16x16x32_bf16(aH, bL, acc[ni], 0, 0, 0);
                acc[ni] = __builtin_amdgcn_mfma_f32_16x16x32_bf16(aL, bH, acc[ni], 0, 0, 0);
            }
        }
        __syncthreads();
    }
    #pragma unroll
    for (int ni = 0; ni < 4; ++ni) {
        int d1 = n0 + ni * 16 + frow;
        #pragma unroll
        for (int e = 0; e < 4; ++e) {
            int d2 = m0 + w * 16 + (lane >> 4) * 4 + e;
            float v = acc[ni][e];
            u16 hi = f2bf(v);
            Mth[(size_t)d2 * 512 + d1] = hi;
            Mtl[(size_t)d2 * 512 + d1] = f2bf(v - bf2f(hi));
        }
    }
}

// ---------------- K2: u = Wk^T @ bq ----------------
__global__ __launch_bounds__(256) void u_kernel(
    const float* __restrict__ Wk, const float* __restrict__ bq,
    float* __restrict__ u) {
    __shared__ float red[4][64];
    const int tid = threadIdx.x, c = tid & 63, hg = tid >> 6;
    const int d2 = blockIdx.x * 64 + c;
    float acc = 0.f;
    for (int h = hg; h < 512; h += 4) acc += Wk[(size_t)h * 512 + d2] * bq[h];
    red[hg][c] = acc;
    __syncthreads();
    if (hg == 0) u[d2] = red[0][c] + red[1][c] + red[2][c] + red[3][c];
}

// ---------------- K3: z = x @ Mt^T + u ----------------
__global__ __launch_bounds__(512) void z_kernel(
    const u16* __restrict__ xh, const u16* __restrict__ xl,
    const u16* __restrict__ Mth, const u16* __restrict__ Mtl,
    const float* __restrict__ u, u16* __restrict__ zh, u16* __restrict__ zl) {
    const int w_ = xcd_swz512((int)blockIdx.x);
    const int bm = w_ >> 2, bn = w_ & 3;
    const int m0 = bm * 128, n0 = bn * 128;
    __shared__ __align__(16) u16 Ah[128 * 64], Al[128 * 64];
    __shared__ __align__(16) u16 Bh[128 * 64], Bl[128 * 64];
    const int tid = threadIdx.x, lane = tid & 63, w = tid >> 6;
    const int rg = w >> 2, cg = w & 3;
    const int frow = lane & 15, fk = (lane >> 4) * 8;
    f32x4 acc[4][2] = {};

    for (int k0 = 0; k0 < 512; k0 += 64) {
        #pragma unroll
        for (int i = 0; i < 2; ++i) {
            int idx = i * 512 + tid;
            int r = idx >> 3, c = idx & 7;
            int sc = (c ^ (r & 7)) * 8;
            gl_lds16(xh + (size_t)(m0 + r) * 512 + k0 + sc, &Ah[idx * 8]);
            gl_lds16(xl + (size_t)(m0 + r) * 512 + k0 + sc, &Al[idx * 8]);
            gl_lds16(Mth + (size_t)(n0 + r) * 512 + k0 + sc, &Bh[idx * 8]);
            gl_lds16(Mtl + (size_t)(n0 + r) * 512 + k0 + sc, &Bl[idx * 8]);
        }
        __syncthreads();
        #pragma unroll
        for (int kk = 0; kk < 2; ++kk) {
            s16x8 aH[4], aL[4], bH[2], bL[2];
            #pragma unroll
            for (int mi = 0; mi < 4; ++mi) {
                int row = rg * 64 + mi * 16 + frow;
                aH[mi] = *(const s16x8*)&Ah[swz64(row, kk * 32 + fk)];
                aL[mi] = *(const s16x8*)&Al[swz64(row, kk * 32 + fk)];
            }
            #pragma unroll
            for (int ni = 0; ni < 2; ++ni) {
                int row = cg * 32 + ni * 16 + frow;
                bH[ni] = *(const s16x8*)&Bh[swz64(row, kk * 32 + fk)];
                bL[ni] = *(const s16x8*)&Bl[swz64(row, kk * 32 + fk)];
            }
            #pragma unroll
            for (int mi = 0; mi < 4; ++mi)
                #pragma unroll
                for (int ni = 0; ni < 2; ++ni) {
                    acc[mi][ni] = __builtin_amdgcn_mfma_f32_16x16x32_bf16(aH[mi], bH[ni], acc[mi][ni], 0, 0, 0);
                    acc[mi][ni] = __builtin_amdgcn_mfma_f32_16x16x32_bf16(aH[mi], bL[ni], acc[mi][ni], 0, 0, 0);
                    acc[mi][ni] = __builtin_amdgcn_mfma_f32_16x16x32_bf16(aL[mi], bH[ni], acc[mi][ni], 0, 0, 0);
                }
        }
        __syncthreads();
    }
    #pragma unroll
    for (int ni = 0; ni < 2; ++ni) {
        int col = n0 + cg * 32 + ni * 16 + frow;
        float uv = u[col];
        #pragma unroll
        for (int mi = 0; mi < 4; ++mi) {
            int rbase = m0 + rg * 64 + mi * 16 + (lane >> 4) * 4;
            #pragma unroll
            for (int e = 0; e < 4; ++e) {
                float v = acc[mi][ni][e] + uv;
                u16 hi = f2bf(v);
                zh[(size_t)(rbase + e) * 512 + col] = hi;
                zl[(size_t)(rbase + e) * 512 + col] = f2bf(v - bf2f(hi));
            }
        }
    }
}

// ---------------- K4: fused banded attention, DIRECT L2 fragment loads ----------------
// grid 512 = 4b x 128 32-row tiles (XCD-swizzled). block 512 (8 waves: 2 rg x 4 quarters).
// No K/V LDS staging: window data is L2/L3-resident (shared 8x between neighbor
// blocks); MFMA B-fragments are loaded straight from global into registers.
// LDS holds only P (32x320 bf16 swizzled) + softmax stats.
__global__ __launch_bounds__(512, 4) void attn_kernel(
    const u16* __restrict__ zh, const u16* __restrict__ zl,
    const u16* __restrict__ xh, const u16* __restrict__ xl,
    const u16* __restrict__ xT, float* __restrict__ out) {
    const int w_ = xcd_swz512((int)blockIdx.x);
    const int b = w_ >> 7, it2 = w_ & 127;
    const int i0 = it2 * 32, j0 = i0 - 128;
    const int mrow0 = b * S_LEN + i0;

    __shared__ __align__(16) u16 PL[32 * 320];      // 20 KB
    __shared__ float sred_max[32 * 4], sred_sum[32 * 4];

    const int tid = threadIdx.x, lane = tid & 63, w = tid >> 6;
    const int g = w >> 2, q = w & 3;
    const int frow = lane & 15, fk = (lane >> 4) * 8;
    const int tstart = g + q * 4;
    const int nt = (q == 3) ? 5 : 4;
    const size_t qoff = (size_t)(mrow0 + g * 16 + frow) * 512;
    const int rq = (lane >> 4) * 4;

    // precompute per-tile clamped global row offsets (wave-invariant per tt)
    size_t rowoffs[5];
    #pragma unroll
    for (int tt = 0; tt < 5; ++tt) {
        int krow = (tstart + tt) * 16 + frow;
        int j = min(max(j0 + krow, 0), S_LEN - 1);
        rowoffs[tt] = (size_t)(b * S_LEN + j) * 512;
    }

    f32x4 acc[5] = {};

    // ---- phase 1: QK^T, 8 chunk-64 steps, fragments direct from L2 ----
    for (int t = 0; t < 8; ++t) {
        const int k0 = t * 64;
        s16x8 zH0 = *(const s16x8*)(zh + qoff + k0 + fk);
        s16x8 zH1 = *(const s16x8*)(zh + qoff + k0 + 32 + fk);
        s16x8 zL0 = *(const s16x8*)(zl + qoff + k0 + fk);
        s16x8 zL1 = *(const s16x8*)(zl + qoff + k0 + 32 + fk);
        #pragma unroll
        for (int kk = 0; kk < 2; ++kk) {
            const int ko = k0 + kk * 32 + fk;
            s16x8 bH[5], bL[5];
            #pragma unroll
            for (int tt = 0; tt < 5; ++tt) {
                if (tt < nt) {
                    bH[tt] = *(const s16x8*)(xh + rowoffs[tt] + ko);
                    bL[tt] = *(const s16x8*)(xl + rowoffs[tt] + ko);
                }
            }
            s16x8 aH = kk ? zH1 : zH0;
            s16x8 aL = kk ? zL1 : zL0;
            __builtin_amdgcn_s_setprio(1);
            #pragma unroll
            for (int tt = 0; tt < 5; ++tt) {
                if (tt < nt) {
                    acc[tt] = __builtin_amdgcn_mfma_f32_16x16x32_bf16(aH, bH[tt], acc[tt], 0, 0, 0);
                    acc[tt] = __builtin_amdgcn_mfma_f32_16x16x32_bf16(aH, bL[tt], acc[tt], 0, 0, 0);
                    acc[tt] = __builtin_amdgcn_mfma_f32_16x16x32_bf16(aL, bH[tt], acc[tt], 0, 0, 0);
                }
            }
            __builtin_amdgcn_s_setprio(0);
        }
    }

    // ---- phase 2: softmax ----
    #pragma unroll
    for (int e = 0; e < 4; ++e) {
        int r = g * 16 + rq + e;
        float m = NEG_INF_F;
        #pragma unroll
        for (int tt = 0; tt < 5; ++tt) {
            if (tt < nt) {
                int jj = (tstart + tt) * 16 + frow;
                int dj = jj - r, j = j0 + jj;
                if (dj >= 1 && dj <= 255 && j >= 0 && j < S_LEN) m = fmaxf(m, acc[tt][e]);
            }
        }
        #pragma unroll
        for (int d = 1; d < 16; d <<= 1) m = fmaxf(m, __shfl_xor(m, d));
        if (frow == 0) sred_max[r * 4 + q] = m;
    }
    __syncthreads();
    float sh[4];
    #pragma unroll
    for (int e = 0; e < 4; ++e) {
        int r = g * 16 + rq + e;
        float mx = fmaxf(fmaxf(sred_max[r * 4], sred_max[r * 4 + 1]),
                         fmaxf(sred_max[r * 4 + 2], sred_max[r * 4 + 3]));
        float s = 0.f;
        #pragma unroll
        for (int tt = 0; tt < 5; ++tt) {
            float pv = 0.f;
            if (tt < nt) {
                int jj = (tstart + tt) * 16 + frow;
                int dj = jj - r, j = j0 + jj;
                bool valid = (dj >= 1 && dj <= 255 && j >= 0 && j < S_LEN);
                pv = valid ? __expf(acc[tt][e] - mx) : 0.f;
            }
            acc[tt][e] = pv;
            s += pv;
        }
        #pragma unroll
        for (int d = 1; d < 16; d <<= 1) s += __shfl_xor(s, d);
        sh[e] = s;
    }
    if (frow == 0) {
        #pragma unroll
        for (int e = 0; e < 4; ++e) sred_sum[(g * 16 + rq + e) * 4 + q] = sh[e];
    }
    __syncthreads();
    float invv[4];
    #pragma unroll
    for (int e = 0; e < 4; ++e) {
        int r = g * 16 + rq + e;
        invv[e] = 1.f / (sred_sum[r * 4] + sred_sum[r * 4 + 1] +
                         sred_sum[r * 4 + 2] + sred_sum[r * 4 + 3]);
    }
    // write normalized P to LDS
    #pragma unroll
    for (int tt = 0; tt < 5; ++tt) {
        if (tt < nt) {
            int t = tstart + tt;
            #pragma unroll
            for (int e = 0; e < 4; ++e) {
                int r = g * 16 + rq + e;
                PL[swz320(r, t * 16 + frow)] = f2bf(acc[tt][e] * invv[e]);
            }
        }
    }
    // zero the one tile this row-group's quarters never wrote (g=0->17, g=1->0)
    if (q == 0) {
        int t = (g == 0) ? 17 : 0;
        int r = g * 16 + frow;
        #pragma unroll
        for (int e2 = 0; e2 < 4; ++e2)
            PL[swz320(r, t * 16 + (lane >> 4) * 4 + e2)] = 0;
    }
    __syncthreads();

    // ---- phase 3: PV, V-fragments direct from xT (L2); no barriers ----
    const int dvrow = q * 16 + frow;                 // d-row within 64-step
    for (int ds = 0; ds < 8; ++ds) {
        const size_t voff = (size_t)(b * 512 + ds * 64 + dvrow) * S_LEN;
        s16x8 bv[9];
        #pragma unroll
        for (int jt = 0; jt < 9; ++jt) {
            int jb = j0 + jt * 32 + fk;
            jb = min(max(jb, 0), S_LEN - 8);         // clamped cols have P==0
            bv[jt] = *(const s16x8*)(xT + voff + jb);
        }
        f32x4 po = {};
        __builtin_amdgcn_s_setprio(1);
        #pragma unroll
        for (int jt = 0; jt < 9; ++jt) {
            s16x8 a = *(const s16x8*)&PL[swz320(g * 16 + frow, jt * 32 + fk)];
            po = __builtin_amdgcn_mfma_f32_16x16x32_bf16(a, bv[jt], po, 0, 0, 0);
        }
        __builtin_amdgcn_s_setprio(0);
        #pragma unroll
        for (int e = 0; e < 4; ++e) {
            int r = mrow0 + g * 16 + rq + e;
            out[(size_t)r * 512 + ds * 64 + q * 16 + frow] = po[e];
        }
    }
}

extern "C" void kernel_launch(void* const* d_in, const int* in_sizes, int n_in,
                              void* d_out, int out_size, void* d_ws, size_t ws_size,
                              hipStream_t stream) {
    const float* x  = (const float*)d_in[0];
    const float* Wq = (const float*)d_in[1];
    const float* bq = (const float*)d_in[2];
    const float* Wk = (const float*)d_in[3];
    const float* bk = (const float*)d_in[4];
    (void)bk;
    float* out = (float*)d_out;

    u16* xh  = (u16*)d_ws;
    u16* xl  = xh + (size_t)8388608;
    u16* zh  = xl + (size_t)8388608;
    u16* zl  = zh + (size_t)8388608;
    u16* Mth = zl + (size_t)8388608;
    u16* Mtl = Mth + (size_t)262144;
    u16* xT  = Mtl + (size_t)262144;
    float* uv = (float*)(xT + (size_t)8388608);

    hipLaunchKernelGGL(split_xt_kernel, dim3(2048), dim3(256), 0, stream, x, xh, xl, xT);
    hipLaunchKernelGGL(mt_kernel, dim3(64), dim3(256), 0, stream, Wk, Wq, Mth, Mtl);
    hipLaunchKernelGGL(u_kernel, dim3(8), dim3(256), 0, stream, Wk, bq, uv);
    hipLaunchKernelGGL(z_kernel, dim3(512), dim3(512), 0, stream,
                       xh, xl, Mth, Mtl, uv, zh, zl);
    hipLaunchKernelGGL(attn_kernel, dim3(512), dim3(512), 0, stream,
                       zh, zl, xh, xl, xT, out);
}

// Round 13
// 137.200 us; speedup vs baseline: 1.4948x; 1.4948x over previous
//
#include <hip/hip_runtime.h>
#include <hip/hip_bf16.h>

#define S_LEN 4096
#define NEG_INF_F (-1e30f)

typedef __attribute__((ext_vector_type(4))) float f32x4;
typedef __attribute__((ext_vector_type(8))) short s16x8;
typedef unsigned short u16;

static __device__ __forceinline__ u16 f2bf(float f) {
    unsigned u = __builtin_bit_cast(unsigned, f);
    unsigned r = u + 0x7FFFu + ((u >> 16) & 1u);
    return (u16)(r >> 16);
}
static __device__ __forceinline__ float bf2f(u16 h) {
    unsigned u = ((unsigned)h) << 16;
    return __builtin_bit_cast(float, u);
}
static __device__ __forceinline__ void split4(const float4 v, ushort4& hi, ushort4& lo) {
    hi.x = f2bf(v.x); lo.x = f2bf(v.x - bf2f(hi.x));
    hi.y = f2bf(v.y); lo.y = f2bf(v.y - bf2f(hi.y));
    hi.z = f2bf(v.z); lo.z = f2bf(v.z - bf2f(hi.z));
    hi.w = f2bf(v.w); lo.w = f2bf(v.w - bf2f(hi.w));
}
static __device__ __forceinline__ void gl_lds16(const void* g, void* l) {
    __builtin_amdgcn_global_load_lds(
        (const __attribute__((address_space(1))) void*)g,
        (__attribute__((address_space(3))) void*)l, 16, 0, 0);
}
// swizzled u16 offset within a [rows][64 u16] LDS tile
static __device__ __forceinline__ int swz64(int row, int col_u16) {
    return row * 64 + (col_u16 ^ ((row & 7) << 3));
}
// swizzled u16 offset within a [rows][32 u16] LDS tile
static __device__ __forceinline__ int swz32(int row, int col_u16) {
    return row * 32 + (col_u16 ^ (((row >> 1) & 3) << 3));
}
// swizzled u16 offset within a [rows][320 u16] LDS tile
static __device__ __forceinline__ int swz320(int row, int col_u16) {
    return row * 320 + (col_u16 ^ ((row & 7) << 3));
}
// XCD-chunked bijective swizzles
static __device__ __forceinline__ int xcd_swz512(int bid) {
    return (bid & 7) * 64 + (bid >> 3);
}
static __device__ __forceinline__ int xcd_swz256(int bid) {
    return (bid & 7) * 32 + (bid >> 3);
}

// ---------------- K0: split x -> xh, xl AND xT (fused transpose) ----------------
__global__ __launch_bounds__(256) void split_xt_kernel(
    const float* __restrict__ x, u16* __restrict__ xh, u16* __restrict__ xl,
    u16* __restrict__ xT) {
    const int bid = blockIdx.x;
    const int dt = bid & 7, st = (bid >> 3) & 63, b = bid >> 9;
    const int s0 = st * 64, d0 = dt * 64;
    __shared__ u16 T[64][72];
    const int tid = threadIdx.x;
    #pragma unroll
    for (int i = 0; i < 4; ++i) {
        int idx = i * 256 + tid;
        int r = idx >> 4, c4 = (idx & 15) * 4;
        float4 v = *(const float4*)(x + (size_t)(b * S_LEN + s0 + r) * 512 + d0 + c4);
        ushort4 hi, lo; split4(v, hi, lo);
        *(ushort4*)(xh + (size_t)(b * S_LEN + s0 + r) * 512 + d0 + c4) = hi;
        *(ushort4*)(xl + (size_t)(b * S_LEN + s0 + r) * 512 + d0 + c4) = lo;
        *(ushort4*)&T[r][c4] = hi;
    }
    __syncthreads();
    #pragma unroll
    for (int i = 0; i < 2; ++i) {
        int idx = i * 256 + tid;
        int dr = idx >> 3, sc = idx & 7;
        s16x8 v;
        #pragma unroll
        for (int t = 0; t < 8; ++t) v[t] = (short)T[sc * 8 + t][dr];
        *(s16x8*)&xT[(size_t)(b * 512 + d0 + dr) * S_LEN + s0 + sc * 8] = v;
    }
}

// ---------------- K1: Mt = Wk^T @ Wq ----------------
__global__ __launch_bounds__(256) void mt_kernel(
    const float* __restrict__ Wk, const float* __restrict__ Wq,
    u16* __restrict__ Mth, u16* __restrict__ Mtl) {
    const int bm = blockIdx.x & 7, bn = blockIdx.x >> 3;
    const int m0 = bm * 64, n0 = bn * 64;
    __shared__ __align__(16) u16 Ath[64 * 72], Atl[64 * 72];
    __shared__ __align__(16) u16 Bth[64 * 72], Btl[64 * 72];
    const int tid = threadIdx.x, lane = tid & 63, w = tid >> 6;
    const int frow = lane & 15, fk = (lane >> 4) * 8;
    f32x4 acc[4] = {};

    for (int h0 = 0; h0 < 512; h0 += 64) {
        #pragma unroll
        for (int i = 0; i < 4; ++i) {
            int idx = i * 256 + tid;
            int h = idx >> 4, c4 = (idx & 15) * 4;
            float4 a = *(const float4*)(Wk + (size_t)(h0 + h) * 512 + m0 + c4);
            ushort4 ahi, alo; split4(a, ahi, alo);
            Ath[(c4 + 0) * 72 + h] = ahi.x; Atl[(c4 + 0) * 72 + h] = alo.x;
            Ath[(c4 + 1) * 72 + h] = ahi.y; Atl[(c4 + 1) * 72 + h] = alo.y;
            Ath[(c4 + 2) * 72 + h] = ahi.z; Atl[(c4 + 2) * 72 + h] = alo.z;
            Ath[(c4 + 3) * 72 + h] = ahi.w; Atl[(c4 + 3) * 72 + h] = alo.w;
            float4 b = *(const float4*)(Wq + (size_t)(h0 + h) * 512 + n0 + c4);
            ushort4 bhi, blo; split4(b, bhi, blo);
            Bth[(c4 + 0) * 72 + h] = bhi.x; Btl[(c4 + 0) * 72 + h] = blo.x;
            Bth[(c4 + 1) * 72 + h] = bhi.y; Btl[(c4 + 1) * 72 + h] = blo.y;
            Bth[(c4 + 2) * 72 + h] = bhi.z; Btl[(c4 + 2) * 72 + h] = blo.z;
            Bth[(c4 + 3) * 72 + h] = bhi.w; Btl[(c4 + 3) * 72 + h] = blo.w;
        }
        __syncthreads();
        #pragma unroll
        for (int kk = 0; kk < 2; ++kk) {
            s16x8 aH = *(const s16x8*)&Ath[(w * 16 + frow) * 72 + kk * 32 + fk];
            s16x8 aL = *(const s16x8*)&Atl[(w * 16 + frow) * 72 + kk * 32 + fk];
            #pragma unroll
            for (int ni = 0; ni < 4; ++ni) {
                s16x8 bH = *(const s16x8*)&Bth[(ni * 16 + frow) * 72 + kk * 32 + fk];
                s16x8 bL = *(const s16x8*)&Btl[(ni * 16 + frow) * 72 + kk * 32 + fk];
                acc[ni] = __builtin_amdgcn_mfma_f32_16x16x32_bf16(aH, bH, acc[ni], 0, 0, 0);
                acc[ni] = __builtin_amdgcn_mfma_f32_16x16x32_bf16(aH, bL, acc[ni], 0, 0, 0);
                acc[ni] = __builtin_amdgcn_mfma_f32_16x16x32_bf16(aL, bH, acc[ni], 0, 0, 0);
            }
        }
        __syncthreads();
    }
    #pragma unroll
    for (int ni = 0; ni < 4; ++ni) {
        int d1 = n0 + ni * 16 + frow;
        #pragma unroll
        for (int e = 0; e < 4; ++e) {
            int d2 = m0 + w * 16 + (lane >> 4) * 4 + e;
            float v = acc[ni][e];
            u16 hi = f2bf(v);
            Mth[(size_t)d2 * 512 + d1] = hi;
            Mtl[(size_t)d2 * 512 + d1] = f2bf(v - bf2f(hi));
        }
    }
}

// ---------------- K2: u = Wk^T @ bq ----------------
__global__ __launch_bounds__(256) void u_kernel(
    const float* __restrict__ Wk, const float* __restrict__ bq,
    float* __restrict__ u) {
    __shared__ float red[4][64];
    const int tid = threadIdx.x, c = tid & 63, hg = tid >> 6;
    const int d2 = blockIdx.x * 64 + c;
    float acc = 0.f;
    for (int h = hg; h < 512; h += 4) acc += Wk[(size_t)h * 512 + d2] * bq[h];
    red[hg][c] = acc;
    __syncthreads();
    if (hg == 0) u[d2] = red[0][c] + red[1][c] + red[2][c] + red[3][c];
}

// ---------------- K3: z = x @ Mt^T + u ----------------
__global__ __launch_bounds__(512) void z_kernel(
    const u16* __restrict__ xh, const u16* __restrict__ xl,
    const u16* __restrict__ Mth, const u16* __restrict__ Mtl,
    const float* __restrict__ u, u16* __restrict__ zh, u16* __restrict__ zl) {
    const int w_ = xcd_swz512((int)blockIdx.x);
    const int bm = w_ >> 2, bn = w_ & 3;
    const int m0 = bm * 128, n0 = bn * 128;
    __shared__ __align__(16) u16 Ah[128 * 64], Al[128 * 64];
    __shared__ __align__(16) u16 Bh[128 * 64], Bl[128 * 64];
    const int tid = threadIdx.x, lane = tid & 63, w = tid >> 6;
    const int rg = w >> 2, cg = w & 3;
    const int frow = lane & 15, fk = (lane >> 4) * 8;
    f32x4 acc[4][2] = {};

    for (int k0 = 0; k0 < 512; k0 += 64) {
        #pragma unroll
        for (int i = 0; i < 2; ++i) {
            int idx = i * 512 + tid;
            int r = idx >> 3, c = idx & 7;
            int sc = (c ^ (r & 7)) * 8;
            gl_lds16(xh + (size_t)(m0 + r) * 512 + k0 + sc, &Ah[idx * 8]);
            gl_lds16(xl + (size_t)(m0 + r) * 512 + k0 + sc, &Al[idx * 8]);
            gl_lds16(Mth + (size_t)(n0 + r) * 512 + k0 + sc, &Bh[idx * 8]);
            gl_lds16(Mtl + (size_t)(n0 + r) * 512 + k0 + sc, &Bl[idx * 8]);
        }
        __syncthreads();
        #pragma unroll
        for (int kk = 0; kk < 2; ++kk) {
            s16x8 aH[4], aL[4], bH[2], bL[2];
            #pragma unroll
            for (int mi = 0; mi < 4; ++mi) {
                int row = rg * 64 + mi * 16 + frow;
                aH[mi] = *(const s16x8*)&Ah[swz64(row, kk * 32 + fk)];
                aL[mi] = *(const s16x8*)&Al[swz64(row, kk * 32 + fk)];
            }
            #pragma unroll
            for (int ni = 0; ni < 2; ++ni) {
                int row = cg * 32 + ni * 16 + frow;
                bH[ni] = *(const s16x8*)&Bh[swz64(row, kk * 32 + fk)];
                bL[ni] = *(const s16x8*)&Bl[swz64(row, kk * 32 + fk)];
            }
            #pragma unroll
            for (int mi = 0; mi < 4; ++mi)
                #pragma unroll
                for (int ni = 0; ni < 2; ++ni) {
                    acc[mi][ni] = __builtin_amdgcn_mfma_f32_16x16x32_bf16(aH[mi], bH[ni], acc[mi][ni], 0, 0, 0);
                    acc[mi][ni] = __builtin_amdgcn_mfma_f32_16x16x32_bf16(aH[mi], bL[ni], acc[mi][ni], 0, 0, 0);
                    acc[mi][ni] = __builtin_amdgcn_mfma_f32_16x16x32_bf16(aL[mi], bH[ni], acc[mi][ni], 0, 0, 0);
                }
        }
        __syncthreads();
    }
    #pragma unroll
    for (int ni = 0; ni < 2; ++ni) {
        int col = n0 + cg * 32 + ni * 16 + frow;
        float uv = u[col];
        #pragma unroll
        for (int mi = 0; mi < 4; ++mi) {
            int rbase = m0 + rg * 64 + mi * 16 + (lane >> 4) * 4;
            #pragma unroll
            for (int e = 0; e < 4; ++e) {
                float v = acc[mi][ni][e] + uv;
                u16 hi = f2bf(v);
                zh[(size_t)(rbase + e) * 512 + col] = hi;
                zl[(size_t)(rbase + e) * 512 + col] = f2bf(v - bf2f(hi));
            }
        }
    }
}

// ---------------- K4: fused banded attention, 64-row tiles, reg-staged ----------------
// grid 256 = 4b x 64 64-row tiles (XCD-swizzled). block 1024 (16 waves: 4 rg x 4 q).
// Window 320 rows. QK^T: 16 chunk-32 steps, LDS dbuf 2x40KB, reg-staged K
// (ds_write at 128B/cyc instead of global_load_lds's 16B/cyc path).
// PV: 8 d-steps of 64 d-rows, reg-staged V. PL/VL/stats alias K buffers.
__global__ __launch_bounds__(1024, 4) void attn_kernel(
    const u16* __restrict__ zh, const u16* __restrict__ zl,
    const u16* __restrict__ xh, const u16* __restrict__ xl,
    const u16* __restrict__ xT, float* __restrict__ out) {
    const int w_ = xcd_swz256((int)blockIdx.x);
    const int b = w_ >> 6, it = w_ & 63;
    const int i0 = it * 64, j0 = i0 - 128;
    const int mrow0 = b * S_LEN + i0;

    __shared__ __align__(16) u16 smem[40960];        // 80 KB
    // QK phase: buf0 = smem[0..20480), buf1 = smem[20480..40960)
    //   each buf: Kh = [320*32] u16 at +0, Kl at +10240
    // PV phase:  PL = smem[0..20480) [64][320], VL = smem[20480..40960) [64][320]
    // stats: alias VL-region start (dead between QK end and first vwrite)

    const int tid = threadIdx.x, lane = tid & 63, w = tid >> 6;
    const int g = w >> 2, q = w & 3;
    const int frow = lane & 15, fk = (lane >> 4) * 8;
    const int tstart = g + q * 4;
    const int nt = (q == 3) ? 5 : 4;
    const size_t qoff = (size_t)(mrow0 + g * 16 + frow) * 512;
    const int rq = (lane >> 4) * 4;

    f32x4 acc[5] = {};
    s16x8 krA[3], krB[3];

    // chunk mapping for one 320x32 hi+lo step: 2560 16B-chunks
    auto kload = [&](int s, s16x8* kr) {
        const int k0 = s * 32;
        #pragma unroll
        for (int i = 0; i < 3; ++i) {
            int f = i * 1024 + tid;
            if (f < 2560) {
                int idx = (f < 1280) ? f : f - 1280;
                int r = idx >> 2, c = idx & 3;
                int j = min(max(j0 + r, 0), S_LEN - 1);
                const u16* src = (f < 1280) ? xh : xl;
                kr[i] = *(const s16x8*)(src + (size_t)(b * S_LEN + j) * 512 + k0 + c * 8);
            }
        }
    };
    auto kwrite = [&](const s16x8* kr, int bufoff) {
        #pragma unroll
        for (int i = 0; i < 3; ++i) {
            int f = i * 1024 + tid;
            if (f < 2560) {
                int idx = (f < 1280) ? f : f - 1280;
                int r = idx >> 2, c = idx & 3;
                int off = bufoff + ((f < 1280) ? 0 : 10240) + swz32(r, c * 8);
                *(s16x8*)&smem[off] = kr[i];
            }
        }
    };
    auto qkstep = [&](int t, int bufoff) {
        const int k0 = t * 32;
        s16x8 zH = *(const s16x8*)(zh + qoff + k0 + fk);
        s16x8 zL = *(const s16x8*)(zl + qoff + k0 + fk);
        __builtin_amdgcn_s_setprio(1);
        #pragma unroll
        for (int tt = 0; tt < 5; ++tt) {
            if (tt < nt) {
                int krow = (tstart + tt) * 16 + frow;
                s16x8 bH = *(const s16x8*)&smem[bufoff + swz32(krow, fk)];
                s16x8 bL = *(const s16x8*)&smem[bufoff + 10240 + swz32(krow, fk)];
                acc[tt] = __builtin_amdgcn_mfma_f32_16x16x32_bf16(zH, bH, acc[tt], 0, 0, 0);
                acc[tt] = __builtin_amdgcn_mfma_f32_16x16x32_bf16(zH, bL, acc[tt], 0, 0, 0);
                acc[tt] = __builtin_amdgcn_mfma_f32_16x16x32_bf16(zL, bH, acc[tt], 0, 0, 0);
            }
        }
        __builtin_amdgcn_s_setprio(0);
    };

    // ---- QK^T: 16 steps, dbuf, reg-staged ----
    kload(0, krA);
    kwrite(krA, 0);
    kload(1, krB);
    __syncthreads();                                 // buf0 ready
    for (int tt2 = 0; tt2 < 16; tt2 += 2) {
        // step tt2 reads buf0; write tile tt2+1 into buf1; load tile tt2+2
        if (tt2 + 1 < 16) kwrite(krB, 20480);
        if (tt2 + 2 < 16) kload(tt2 + 2, krA);
        qkstep(tt2, 0);
        __syncthreads();                             // buf1 ready, buf0 free
        // step tt2+1 reads buf1; write tile tt2+2 into buf0; load tile tt2+3
        if (tt2 + 1 < 16) {
            if (tt2 + 2 < 16) kwrite(krA, 0);
            if (tt2 + 3 < 16) kload(tt2 + 3, krB);
            qkstep(tt2 + 1, 20480);
            __syncthreads();                         // buf0 ready, buf1 free
        }
    }

    // ---- softmax (stats alias VL region; PL region disjoint) ----
    float* sred_max = (float*)&smem[20480];          // [64][4]
    float* sred_sum = sred_max + 256;                // [64][4]
    #pragma unroll
    for (int e = 0; e < 4; ++e) {
        int r = g * 16 + rq + e;
        float m = NEG_INF_F;
        #pragma unroll
        for (int tt = 0; tt < 5; ++tt) {
            if (tt < nt) {
                int jj = (tstart + tt) * 16 + frow;
                int dj = jj - r, j = j0 + jj;
                if (dj >= 1 && dj <= 255 && j >= 0 && j < S_LEN) m = fmaxf(m, acc[tt][e]);
            }
        }
        #pragma unroll
        for (int d = 1; d < 16; d <<= 1) m = fmaxf(m, __shfl_xor(m, d));
        if (frow == 0) sred_max[r * 4 + q] = m;
    }
    __syncthreads();
    float sh[4];
    #pragma unroll
    for (int e = 0; e < 4; ++e) {
        int r = g * 16 + rq + e;
        float mx = fmaxf(fmaxf(sred_max[r * 4], sred_max[r * 4 + 1]),
                         fmaxf(sred_max[r * 4 + 2], sred_max[r * 4 + 3]));
        float s = 0.f;
        #pragma unroll
        for (int tt = 0; tt < 5; ++tt) {
            float pv = 0.f;
            if (tt < nt) {
                int jj = (tstart + tt) * 16 + frow;
                int dj = jj - r, j = j0 + jj;
                bool valid = (dj >= 1 && dj <= 255 && j >= 0 && j < S_LEN);
                pv = valid ? __expf(acc[tt][e] - mx) : 0.f;
            }
            acc[tt][e] = pv;
            s += pv;
        }
        #pragma unroll
        for (int d = 1; d < 16; d <<= 1) s += __shfl_xor(s, d);
        sh[e] = s;
    }
    if (frow == 0) {
        #pragma unroll
        for (int e = 0; e < 4; ++e) sred_sum[(g * 16 + rq + e) * 4 + q] = sh[e];
    }
    __syncthreads();
    float invv[4];
    #pragma unroll
    for (int e = 0; e < 4; ++e) {
        int r = g * 16 + rq + e;
        invv[e] = 1.f / (sred_sum[r * 4] + sred_sum[r * 4 + 1] +
                         sred_sum[r * 4 + 2] + sred_sum[r * 4 + 3]);
    }
    __syncthreads();                                 // stats consumed before VL writes
    // write normalized P into PL = smem[0..20480)
    #pragma unroll
    for (int tt = 0; tt < 5; ++tt) {
        if (tt < nt) {
            int t = tstart + tt;
            #pragma unroll
            for (int e = 0; e < 4; ++e) {
                int r = g * 16 + rq + e;
                smem[swz320(r, t * 16 + frow)] = f2bf(acc[tt][e] * invv[e]);
            }
        }
    }
    // band-complement zero-fill: tiles [0,g) by q0, tiles [g+17,20) by q3
    if (q == 0) {
        for (int t = 0; t < g; ++t)
            #pragma unroll
            for (int e = 0; e < 4; ++e)
                smem[swz320(g * 16 + rq + e, t * 16 + frow)] = 0;
    }
    if (q == 3) {
        for (int t = g + 17; t < 20; ++t)
            #pragma unroll
            for (int e = 0; e < 4; ++e)
                smem[swz320(g * 16 + rq + e, t * 16 + frow)] = 0;
    }

    // ---- PV: 8 d-steps of 64 d-rows, reg-staged V into VL ----
    s16x8 vreg[3];
    auto vload = [&](int ds) {
        const int d0 = ds * 64;
        #pragma unroll
        for (int i = 0; i < 3; ++i) {
            int f = i * 1024 + tid;                  // 2560 chunks (64 rows x 40)
            if (f < 2560) {
                int dr = f / 40, c8 = f - dr * 40;
                int jb = j0 + c8 * 8;
                jb = min(max(jb, 0), S_LEN - 8);     // clamped chunks have P==0
                vreg[i] = *(const s16x8*)&xT[(size_t)(b * 512 + d0 + dr) * S_LEN + jb];
            }
        }
    };
    auto vwrite = [&]() {
        #pragma unroll
        for (int i = 0; i < 3; ++i) {
            int f = i * 1024 + tid;
            if (f < 2560) {
                int dr = f / 40, c8 = f - dr * 40;
                *(s16x8*)&smem[20480 + swz320(dr, c8 * 8)] = vreg[i];
            }
        }
    };
    vload(0);
    for (int ds = 0; ds < 8; ++ds) {
        __syncthreads();                 // PL ready (ds=0) / prev VL reads done
        vwrite();
        __syncthreads();                 // VL visible
        if (ds < 7) vload(ds + 1);       // flies under this step's MFMA
        f32x4 po = {};
        __builtin_amdgcn_s_setprio(1);
        #pragma unroll
        for (int jt = 0; jt < 10; ++jt) {
            s16x8 a = *(const s16x8*)&smem[swz320(g * 16 + frow, jt * 32 + fk)];
            s16x8 bv = *(const s16x8*)&smem[20480 + swz320(q * 16 + frow, jt * 32 + fk)];
            po = __builtin_amdgcn_mfma_f32_16x16x32_bf16(a, bv, po, 0, 0, 0);
        }
        __builtin_amdgcn_s_setprio(0);
        #pragma unroll
        for (int e = 0; e < 4; ++e) {
            int r = mrow0 + g * 16 + rq + e;
            out[(size_t)r * 512 + ds * 64 + q * 16 + frow] = po[e];
        }
    }
}

extern "C" void kernel_launch(void* const* d_in, const int* in_sizes, int n_in,
                              void* d_out, int out_size, void* d_ws, size_t ws_size,
                              hipStream_t stream) {
    const float* x  = (const float*)d_in[0];
    const float* Wq = (const float*)d_in[1];
    const float* bq = (const float*)d_in[2];
    const float* Wk = (const float*)d_in[3];
    const float* bk = (const float*)d_in[4];
    (void)bk;
    float* out = (float*)d_out;

    u16* xh  = (u16*)d_ws;
    u16* xl  = xh + (size_t)8388608;
    u16* zh  = xl + (size_t)8388608;
    u16* zl  = zh + (size_t)8388608;
    u16* Mth = zl + (size_t)8388608;
    u16* Mtl = Mth + (size_t)262144;
    u16* xT  = Mtl + (size_t)262144;
    float* uv = (float*)(xT + (size_t)8388608);

    hipLaunchKernelGGL(split_xt_kernel, dim3(2048), dim3(256), 0, stream, x, xh, xl, xT);
    hipLaunchKernelGGL(mt_kernel, dim3(64), dim3(256), 0, stream, Wk, Wq, Mth, Mtl);
    hipLaunchKernelGGL(u_kernel, dim3(8), dim3(256), 0, stream, Wk, bq, uv);
    hipLaunchKernelGGL(z_kernel, dim3(512), dim3(512), 0, stream,
                       xh, xl, Mth, Mtl, uv, zh, zl);
    hipLaunchKernelGGL(attn_kernel, dim3(256), dim3(1024), 0, stream,
                       zh, zl, xh, xl, xT, out);
}